// Round 6
// baseline (131.010 us; speedup 1.0000x reference)
//
#include <hip/hip_runtime.h>
#include <math.h>

#define N_PROP 1000
#define NUM_CLASSES 81
#define NFG 80
#define SCORE_THRESH 0.05f
#define NMS_THRESH 0.5f
#define DET_PER_IMG 100
#define PER_CLASS_CAP 100
#define KEPT_CAP (NFG * PER_CLASS_CAP)   /* 8000, fixed */
#define NBLK 80
// log(1000/16)
#define BBOX_XFORM_CLIP 4.135166556742356f

// Device-scope software grid barrier. All NBLK blocks are co-resident
// (80 blocks x 256 thr, 64KB LDS -> >=1 block/CU on 256 CUs).
// bar must be zeroed before the kernel (16B memset); one counter per sync.
__device__ __forceinline__ void grid_sync(int* bar) {
    __threadfence();                     // release this thread's stores (agent scope)
    __syncthreads();
    if (threadIdx.x == 0) {
        __hip_atomic_fetch_add(bar, 1, __ATOMIC_ACQ_REL, __HIP_MEMORY_SCOPE_AGENT);
        while (__hip_atomic_load(bar, __ATOMIC_ACQUIRE, __HIP_MEMORY_SCOPE_AGENT) < NBLK) {}
    }
    __syncthreads();
    __threadfence();                     // acquire: invalidate L1 before reading peers' data
}

__global__ __launch_bounds__(256, 1) void k_fused(
    const float* __restrict__ logits,   // [N_PROP, 81]
    const float* __restrict__ deltas,   // [N_PROP, 324]
    const float* __restrict__ pboxes,   // [N_PROP, 4]
    const int* __restrict__ ih, const int* __restrict__ iw,
    int* __restrict__ bar,              // [4], zeroed by memset node
    float* __restrict__ candS,          // [NFG][N_PROP]
    float* __restrict__ keptScore,      // [KEPT_CAP]
    unsigned* __restrict__ keptKey,     // [KEPT_CAP]
    float4* __restrict__ keptBox,       // [KEPT_CAP]
    float* __restrict__ out)            // [100] scores | [400] boxes | [100] labels
{
    const int b   = blockIdx.x;          // == class c in phases 2/3
    const int tid = threadIdx.x;

    __shared__ float redm[2][2];
    __shared__ float reds[2][2];
    __shared__ int   cnt;
    union SMem {
        struct {
            float ss[N_PROP];            // candidate scores (unsorted)
            int   si[N_PROP];            // candidate proposal idx
            float sb[N_PROP * 4];        // candidate boxes (unsorted)
            float os[N_PROP];            // sorted scores
            float ob[N_PROP * 4];        // sorted boxes
            int   ok[N_PROP];            // kept flags
        } p2;                            // 48000 B
        unsigned long long pk[KEPT_CAP]; // 64000 B
    };
    __shared__ SMem u;

    // ---------------- Phase 1: softmax -> dense candS ----------------
    // Block b handles proposals n = b + 80*r, r=0..12. Two 128-thread
    // halves process two proposals per round (R3's 2-wave shuffle softmax).
    {
        const int half = tid >> 7;       // 0/1
        const int t    = tid & 127;      // lane within half
        const int wh   = t >> 6;         // wave within half
        for (int p = 0; p < 7; ++p) {
            const int r = 2 * p + half;
            const int n = b + 80 * r;
            const bool act = (n < N_PROP);
            float l = (act && t < NUM_CLASSES) ? logits[n * NUM_CLASSES + t]
                                               : -INFINITY;
            float m = l;
            #pragma unroll
            for (int o = 32; o > 0; o >>= 1) m = fmaxf(m, __shfl_xor(m, o));
            if ((t & 63) == 0) redm[half][wh] = m;
            __syncthreads();
            m = fmaxf(redm[half][0], redm[half][1]);

            float e = (act && t < NUM_CLASSES) ? expf(l - m) : 0.0f;
            float s = e;
            #pragma unroll
            for (int o = 32; o > 0; o >>= 1) s += __shfl_xor(s, o);
            if ((t & 63) == 0) reds[half][wh] = s;
            __syncthreads();
            s = reds[half][0] + reds[half][1];

            if (act && t >= 1 && t < NUM_CLASSES) {
                const float prob = e / s;
                candS[(size_t)(t - 1) * N_PROP + n] =
                    (prob > SCORE_THRESH) ? prob : 0.0f;
            }
        }
    }

    grid_sync(&bar[0]);

    // ---------------- Phase 2: per-class compact + decode + sort + NMS ----
    const int c   = b;
    const int cls = c + 1;
    if (tid == 0) cnt = 0;
    __syncthreads();

    const float W = (float)iw[0] - 1.0f;
    const float H = (float)ih[0] - 1.0f;

    for (int n = tid; n < N_PROP; n += 256) {
        const float p = candS[(size_t)c * N_PROP + n];
        if (p > 0.0f) {
            // re-decode box for this (class, proposal) hit
            const float x1b = pboxes[n * 4 + 0];
            const float y1b = pboxes[n * 4 + 1];
            const float x2b = pboxes[n * 4 + 2];
            const float y2b = pboxes[n * 4 + 3];
            const float w  = x2b - x1b + 1.0f;
            const float h  = y2b - y1b + 1.0f;
            const float cx = x1b + 0.5f * w;
            const float cy = y1b + 0.5f * h;
            const float* d = deltas + (size_t)n * (NUM_CLASSES * 4) + cls * 4;
            const float dx = d[0] / 10.0f;
            const float dy = d[1] / 10.0f;
            const float dw = fminf(d[2] / 5.0f, BBOX_XFORM_CLIP);
            const float dh = fminf(d[3] / 5.0f, BBOX_XFORM_CLIP);
            const float pcx = dx * w + cx;
            const float pcy = dy * h + cy;
            const float pw  = expf(dw) * w;
            const float ph  = expf(dh) * h;
            float X1 = pcx - 0.5f * pw;
            float Y1 = pcy - 0.5f * ph;
            float X2 = pcx + 0.5f * pw - 1.0f;
            float Y2 = pcy + 0.5f * ph - 1.0f;
            X1 = fminf(fmaxf(X1, 0.0f), W);
            Y1 = fminf(fmaxf(Y1, 0.0f), H);
            X2 = fminf(fmaxf(X2, 0.0f), W);
            Y2 = fminf(fmaxf(Y2, 0.0f), H);

            const int pos = atomicAdd(&cnt, 1);
            u.p2.ss[pos] = p;
            u.p2.si[pos] = n;
            u.p2.sb[pos * 4 + 0] = X1;
            u.p2.sb[pos * 4 + 1] = Y1;
            u.p2.sb[pos * 4 + 2] = X2;
            u.p2.sb[pos * 4 + 3] = Y2;
        }
    }
    __syncthreads();
    const int M = cnt;

    // rank sort: (score desc, prop_idx asc) — matches stable argsort(-s)
    for (int i = tid; i < M; i += 256) {
        const float s0 = u.p2.ss[i];
        const int   i0 = u.p2.si[i];
        int r = 0;
        for (int j = 0; j < M; ++j) {
            const float sj = u.p2.ss[j];
            r += (sj > s0) || (sj == s0 && u.p2.si[j] < i0);
        }
        u.p2.os[r] = s0;
        u.p2.ob[r * 4 + 0] = u.p2.sb[i * 4 + 0];
        u.p2.ob[r * 4 + 1] = u.p2.sb[i * 4 + 1];
        u.p2.ob[r * 4 + 2] = u.p2.sb[i * 4 + 2];
        u.p2.ob[r * 4 + 3] = u.p2.sb[i * 4 + 3];
        u.p2.ok[r] = 1;
    }
    __syncthreads();

    // greedy NMS: sequential over i, parallel suppression of j > i
    for (int i = 0; i < M; ++i) {
        if (u.p2.ok[i]) {
            const float ax1 = u.p2.ob[i * 4 + 0], ay1 = u.p2.ob[i * 4 + 1];
            const float ax2 = u.p2.ob[i * 4 + 2], ay2 = u.p2.ob[i * 4 + 3];
            const float aarea = (ax2 - ax1 + 1.0f) * (ay2 - ay1 + 1.0f);
            for (int j = i + 1 + tid; j < M; j += 256) {
                const float bx1 = u.p2.ob[j * 4 + 0], by1 = u.p2.ob[j * 4 + 1];
                const float bx2 = u.p2.ob[j * 4 + 2], by2 = u.p2.ob[j * 4 + 3];
                const float barea = (bx2 - bx1 + 1.0f) * (by2 - by1 + 1.0f);
                const float ix1 = fmaxf(ax1, bx1), iy1 = fmaxf(ay1, by1);
                const float ix2 = fminf(ax2, bx2), iy2 = fminf(ay2, by2);
                const float iw_ = fmaxf(ix2 - ix1 + 1.0f, 0.0f);
                const float ih_ = fmaxf(iy2 - iy1 + 1.0f, 0.0f);
                const float inter = iw_ * ih_;
                const float iou = inter / (aarea + barea - inter);
                if (iou > NMS_THRESH) u.p2.ok[j] = 0;
            }
        }
        __syncthreads();
    }

    // write survivors to fixed per-class slots; zero-fill the rest
    for (int i = tid; i < M; i += 256) {
        if (u.p2.ok[i]) {
            int sr = 0;
            for (int j = 0; j < i; ++j) sr += u.p2.ok[j];
            if (sr < PER_CLASS_CAP) {
                const int slot = c * PER_CLASS_CAP + sr;
                keptScore[slot] = u.p2.os[i];
                keptKey[slot]   = (unsigned)(c * N_PROP + i);
                keptBox[slot]   = make_float4(u.p2.ob[i * 4 + 0], u.p2.ob[i * 4 + 1],
                                              u.p2.ob[i * 4 + 2], u.p2.ob[i * 4 + 3]);
            }
        }
    }
    int S = 0;
    for (int j = 0; j < M; ++j) S += u.p2.ok[j];
    if (S > PER_CLASS_CAP) S = PER_CLASS_CAP;
    for (int s = S + tid; s < PER_CLASS_CAP; s += 256) {
        const int slot = c * PER_CLASS_CAP + s;
        keptScore[slot] = 0.0f;                       // invalid marker
        keptKey[slot]   = (unsigned)(c * N_PROP + s); // distinct key
        keptBox[slot]   = make_float4(0.0f, 0.0f, 0.0f, 0.0f);
    }

    grid_sync(&bar[1]);

    // ---------------- Phase 3: global top-100 via LDS rank ----------------
    // Block c ranks its own 100 fixed slots against all 8000 packed keys.
    // All packed keys are distinct -> each rank 0..99 gets exactly one
    // writer -> d_out fully written every call.
    for (int j = tid; j < KEPT_CAP; j += 256) {
        u.pk[j] = ((unsigned long long)__float_as_uint(keptScore[j]) << 32)
                | (unsigned)(~keptKey[j]);
    }
    __syncthreads();

    if (tid < 2 * PER_CLASS_CAP) {
        const int e    = c * PER_CLASS_CAP + (tid >> 1);
        const int part = tid & 1;
        const unsigned long long mykey = u.pk[e];

        const int lo = part * (KEPT_CAP / 2);
        const int hi = lo + (KEPT_CAP / 2);
        int r = 0;
        for (int j = lo; j + 8 <= hi; j += 8) {
            const unsigned long long k0 = u.pk[j + 0];
            const unsigned long long k1 = u.pk[j + 1];
            const unsigned long long k2 = u.pk[j + 2];
            const unsigned long long k3 = u.pk[j + 3];
            const unsigned long long k4 = u.pk[j + 4];
            const unsigned long long k5 = u.pk[j + 5];
            const unsigned long long k6 = u.pk[j + 6];
            const unsigned long long k7 = u.pk[j + 7];
            r += (int)(k0 > mykey) + (int)(k1 > mykey)
               + (int)(k2 > mykey) + (int)(k3 > mykey)
               + (int)(k4 > mykey) + (int)(k5 > mykey)
               + (int)(k6 > mykey) + (int)(k7 > mykey);
        }
        r += __shfl_xor(r, 1);

        if (part == 0 && r < DET_PER_IMG) {
            const float sc = keptScore[e];
            const bool valid = sc > 0.0f;
            out[r] = sc;
            const float4 bb = keptBox[e];
            out[DET_PER_IMG + r * 4 + 0] = bb.x;
            out[DET_PER_IMG + r * 4 + 1] = bb.y;
            out[DET_PER_IMG + r * 4 + 2] = bb.z;
            out[DET_PER_IMG + r * 4 + 3] = bb.w;
            const unsigned key = keptKey[e];
            out[DET_PER_IMG * 5 + r] = valid ? (float)(key / N_PROP + 1) : 0.0f;
        }
    }
}

extern "C" void kernel_launch(void* const* d_in, const int* in_sizes, int n_in,
                              void* d_out, int out_size, void* d_ws, size_t ws_size,
                              hipStream_t stream) {
    const float* logits = (const float*)d_in[0];
    const float* deltas = (const float*)d_in[1];
    const float* pboxes = (const float*)d_in[2];
    const int*   ih     = (const int*)d_in[3];
    const int*   iw     = (const int*)d_in[4];
    float* out = (float*)d_out;

    // workspace layout
    int* bar = (int*)d_ws;                               // [0..3], memset below
    char* p = (char*)d_ws + 256;
    float4*   keptBox   = (float4*)p;    p += (size_t)KEPT_CAP * 16;
    float*    candS     = (float*)p;     p += (size_t)NFG * N_PROP * 4;
    float*    keptScore = (float*)p;     p += (size_t)KEPT_CAP * 4;
    unsigned* keptKey   = (unsigned*)p;  p += (size_t)KEPT_CAP * 4;

    hipMemsetAsync(bar, 0, 16, stream);                  // zero both barrier counters
    k_fused<<<NBLK, 256, 0, stream>>>(logits, deltas, pboxes, ih, iw,
                                      bar, candS, keptScore, keptKey, keptBox, out);
}

// Round 7
// 73.614 us; speedup vs baseline: 1.7797x; 1.7797x over previous
//
#include <hip/hip_runtime.h>
#include <math.h>

#define N_PROP 1000
#define NUM_CLASSES 81
#define NFG 80
#define SCORE_THRESH 0.05f
#define NMS_THRESH 0.5f
#define DET_PER_IMG 100
#define PER_CLASS_CAP 100
#define KEPT_CAP (NFG * PER_CLASS_CAP)   /* 8000, fixed */
#define MBITS 512                        /* bitmask NMS path when M <= MBITS */
// log(1000/16)
#define BBOX_XFORM_CLIP 4.135166556742356f

// ---------------- Kernel 1: parallel softmax -> dense score grid ----------
// grid = N_PROP blocks, 128 threads. Lane t handles class t for proposal n.
// Writes ALL 80 score slots (0 when below threshold) -> no counters/memsets.
__global__ __launch_bounds__(128) void k_decode(
    const float* __restrict__ logits,   // [N_PROP, 81]
    float* __restrict__ candS)          // [NFG][N_PROP]
{
    const int n = blockIdx.x;
    const int t = threadIdx.x;
    __shared__ float redm[2];
    __shared__ float reds[2];

    float l = (t < NUM_CLASSES) ? logits[n * NUM_CLASSES + t] : -INFINITY;

    float m = l;
    #pragma unroll
    for (int o = 32; o > 0; o >>= 1) m = fmaxf(m, __shfl_xor(m, o));
    const int wave = t >> 6;
    if ((t & 63) == 0) redm[wave] = m;
    __syncthreads();
    m = fmaxf(redm[0], redm[1]);

    float e = (t < NUM_CLASSES) ? expf(l - m) : 0.0f;
    float s = e;
    #pragma unroll
    for (int o = 32; o > 0; o >>= 1) s += __shfl_xor(s, o);
    if ((t & 63) == 0) reds[wave] = s;
    __syncthreads();
    s = reds[0] + reds[1];

    if (t >= 1 && t < NUM_CLASSES) {
        const float prob = e / s;
        candS[(size_t)(t - 1) * N_PROP + n] = (prob > SCORE_THRESH) ? prob : 0.0f;
    }
}

// ---------------- Kernel 2: per-class compact+decode+sort + bitmask NMS ---
// grid = NFG blocks, 256 threads. Writes ALL PER_CLASS_CAP slots per class.
__global__ __launch_bounds__(256) void k_nms(
    const float* __restrict__ candS,
    const float* __restrict__ deltas,   // [N_PROP, 324]
    const float* __restrict__ pboxes,   // [N_PROP, 4]
    const int* __restrict__ ih, const int* __restrict__ iw,
    float* __restrict__ keptScore,      // [KEPT_CAP]
    unsigned* __restrict__ keptKey,     // [KEPT_CAP]
    float4* __restrict__ keptBox)       // [KEPT_CAP]
{
    const int c   = blockIdx.x;
    const int cls = c + 1;
    const int tid = threadIdx.x;

    // msk (32 KB) unioned over the pre-sort arrays (24 KB) — dead after sort
    __shared__ union {
        struct { float ss[N_PROP]; int si[N_PROP]; float sb[N_PROP * 4]; } in;
        unsigned long long msk[MBITS * (MBITS / 64)];   // [M][NW] row bitmasks
    } u;
    __shared__ float os[N_PROP];        // sorted scores
    __shared__ float ob[N_PROP * 4];    // sorted boxes
    __shared__ unsigned long long keepw_s[16];
    __shared__ int cnt;

    if (tid == 0) cnt = 0;
    __syncthreads();

    const float W = (float)iw[0] - 1.0f;
    const float H = (float)ih[0] - 1.0f;

    // compact + re-decode boxes for hits only (~M per class)
    for (int n = tid; n < N_PROP; n += 256) {
        const float p = candS[(size_t)c * N_PROP + n];
        if (p > 0.0f) {
            const float x1b = pboxes[n * 4 + 0];
            const float y1b = pboxes[n * 4 + 1];
            const float x2b = pboxes[n * 4 + 2];
            const float y2b = pboxes[n * 4 + 3];
            const float w  = x2b - x1b + 1.0f;
            const float h  = y2b - y1b + 1.0f;
            const float cx = x1b + 0.5f * w;
            const float cy = y1b + 0.5f * h;
            const float* d = deltas + (size_t)n * (NUM_CLASSES * 4) + cls * 4;
            const float dx = d[0] / 10.0f;
            const float dy = d[1] / 10.0f;
            const float dw = fminf(d[2] / 5.0f, BBOX_XFORM_CLIP);
            const float dh = fminf(d[3] / 5.0f, BBOX_XFORM_CLIP);
            const float pcx = dx * w + cx;
            const float pcy = dy * h + cy;
            const float pw  = expf(dw) * w;
            const float ph  = expf(dh) * h;
            float X1 = pcx - 0.5f * pw;
            float Y1 = pcy - 0.5f * ph;
            float X2 = pcx + 0.5f * pw - 1.0f;
            float Y2 = pcy + 0.5f * ph - 1.0f;
            X1 = fminf(fmaxf(X1, 0.0f), W);
            Y1 = fminf(fmaxf(Y1, 0.0f), H);
            X2 = fminf(fmaxf(X2, 0.0f), W);
            Y2 = fminf(fmaxf(Y2, 0.0f), H);

            const int pos = atomicAdd(&cnt, 1);
            u.in.ss[pos] = p;
            u.in.si[pos] = n;
            u.in.sb[pos * 4 + 0] = X1;
            u.in.sb[pos * 4 + 1] = Y1;
            u.in.sb[pos * 4 + 2] = X2;
            u.in.sb[pos * 4 + 3] = Y2;
        }
    }
    __syncthreads();
    const int M = cnt;

    // rank sort: (score desc, prop_idx asc) — matches stable argsort(-s)
    for (int i = tid; i < M; i += 256) {
        const float s0 = u.in.ss[i];
        const int   i0 = u.in.si[i];
        int r = 0;
        for (int j = 0; j < M; ++j) {
            const float sj = u.in.ss[j];
            r += (sj > s0) || (sj == s0 && u.in.si[j] < i0);
        }
        os[r] = s0;
        ob[r * 4 + 0] = u.in.sb[i * 4 + 0];
        ob[r * 4 + 1] = u.in.sb[i * 4 + 1];
        ob[r * 4 + 2] = u.in.sb[i * 4 + 2];
        ob[r * 4 + 3] = u.in.sb[i * 4 + 3];
    }
    __syncthreads();                    // u.in dead from here; u.msk live

    if (M <= MBITS) {
        // ---- bitmask NMS: parallel mask build, barrier-free wave sweep ----
        const int NW = (M + 63) >> 6;   // words per row

        for (int idx = tid; idx < M * NW; idx += 256) {
            const int i = idx / NW;
            const int w = idx - i * NW;
            const float ax1 = ob[i * 4 + 0], ay1 = ob[i * 4 + 1];
            const float ax2 = ob[i * 4 + 2], ay2 = ob[i * 4 + 3];
            const float aarea = (ax2 - ax1 + 1.0f) * (ay2 - ay1 + 1.0f);
            unsigned long long bits = 0;
            const int j0 = w << 6;
            const int jb = (i + 1 > j0) ? (i + 1) : j0;
            const int je = (j0 + 64 < M) ? (j0 + 64) : M;
            for (int j = jb; j < je; ++j) {
                const float bx1 = ob[j * 4 + 0], by1 = ob[j * 4 + 1];
                const float bx2 = ob[j * 4 + 2], by2 = ob[j * 4 + 3];
                const float barea = (bx2 - bx1 + 1.0f) * (by2 - by1 + 1.0f);
                const float ix1 = fmaxf(ax1, bx1), iy1 = fmaxf(ay1, by1);
                const float ix2 = fminf(ax2, bx2), iy2 = fminf(ay2, by2);
                const float iw_ = fmaxf(ix2 - ix1 + 1.0f, 0.0f);
                const float ih_ = fmaxf(iy2 - iy1 + 1.0f, 0.0f);
                const float inter = iw_ * ih_;
                const float iou = inter / (aarea + barea - inter);
                if (iou > NMS_THRESH) bits |= 1ull << (j - j0);
            }
            u.msk[i * NW + w] = bits;
        }
        __syncthreads();

        // sweep on wave 0: lane l holds keep-word l in a register.
        if (tid < 64) {
            const int l = tid;
            const int base = l << 6;
            int nb = M - base;
            nb = nb < 0 ? 0 : (nb > 64 ? 64 : nb);
            unsigned long long keepw =
                (nb == 64) ? ~0ull : ((nb == 0) ? 0ull : ((1ull << nb) - 1ull));
            for (int i = 0; i < M; ++i) {
                const unsigned long long kb = __shfl(keepw, i >> 6);
                if ((kb >> (i & 63)) & 1ull) {
                    const unsigned long long mrow =
                        (l < NW) ? u.msk[i * NW + l] : 0ull;
                    keepw &= ~mrow;
                }
            }
            if (l < 16) keepw_s[l] = keepw;
        }
        __syncthreads();

        unsigned long long kw[16];
        #pragma unroll
        for (int w = 0; w < 16; ++w) kw[w] = keepw_s[w];
        int S = 0;
        #pragma unroll
        for (int w = 0; w < 16; ++w) S += __popcll(kw[w]);
        if (S > PER_CLASS_CAP) S = PER_CLASS_CAP;

        for (int i = tid; i < M; i += 256) {
            const int w = i >> 6, b = i & 63;
            if ((kw[w] >> b) & 1ull) {
                int sr = 0;
                for (int ww = 0; ww < w; ++ww) sr += __popcll(kw[ww]);
                sr += __popcll(kw[w] & ((b == 0) ? 0ull : (~0ull >> (64 - b))));
                if (sr < PER_CLASS_CAP) {
                    const int slot = c * PER_CLASS_CAP + sr;
                    keptScore[slot] = os[i];
                    keptKey[slot]   = (unsigned)(c * N_PROP + i);
                    keptBox[slot]   = make_float4(ob[i * 4 + 0], ob[i * 4 + 1],
                                                  ob[i * 4 + 2], ob[i * 4 + 3]);
                }
            }
        }
        for (int s = S + tid; s < PER_CLASS_CAP; s += 256) {
            const int slot = c * PER_CLASS_CAP + s;
            keptScore[slot] = 0.0f;
            keptKey[slot]   = (unsigned)(c * N_PROP + s);
            keptBox[slot]   = make_float4(0.0f, 0.0f, 0.0f, 0.0f);
        }
    } else {
        // ---- legacy serial path (M > 512; never hit by this data) ----
        int* ok = (int*)u.msk;
        for (int i = tid; i < M; i += 256) ok[i] = 1;
        __syncthreads();
        for (int i = 0; i < M; ++i) {
            if (ok[i]) {
                const float ax1 = ob[i * 4 + 0], ay1 = ob[i * 4 + 1];
                const float ax2 = ob[i * 4 + 2], ay2 = ob[i * 4 + 3];
                const float aarea = (ax2 - ax1 + 1.0f) * (ay2 - ay1 + 1.0f);
                for (int j = i + 1 + tid; j < M; j += 256) {
                    const float bx1 = ob[j * 4 + 0], by1 = ob[j * 4 + 1];
                    const float bx2 = ob[j * 4 + 2], by2 = ob[j * 4 + 3];
                    const float barea = (bx2 - bx1 + 1.0f) * (by2 - by1 + 1.0f);
                    const float ix1 = fmaxf(ax1, bx1), iy1 = fmaxf(ay1, by1);
                    const float ix2 = fminf(ax2, bx2), iy2 = fminf(ay2, by2);
                    const float iw_ = fmaxf(ix2 - ix1 + 1.0f, 0.0f);
                    const float ih_ = fmaxf(iy2 - iy1 + 1.0f, 0.0f);
                    const float inter = iw_ * ih_;
                    const float iou = inter / (aarea + barea - inter);
                    if (iou > NMS_THRESH) ok[j] = 0;
                }
            }
            __syncthreads();
        }
        for (int i = tid; i < M; i += 256) {
            if (ok[i]) {
                int sr = 0;
                for (int j = 0; j < i; ++j) sr += ok[j];
                if (sr < PER_CLASS_CAP) {
                    const int slot = c * PER_CLASS_CAP + sr;
                    keptScore[slot] = os[i];
                    keptKey[slot]   = (unsigned)(c * N_PROP + i);
                    keptBox[slot]   = make_float4(ob[i * 4 + 0], ob[i * 4 + 1],
                                                  ob[i * 4 + 2], ob[i * 4 + 3]);
                }
            }
        }
        int S = 0;
        for (int j = 0; j < M; ++j) S += ok[j];
        if (S > PER_CLASS_CAP) S = PER_CLASS_CAP;
        for (int s = S + tid; s < PER_CLASS_CAP; s += 256) {
            const int slot = c * PER_CLASS_CAP + s;
            keptScore[slot] = 0.0f;
            keptKey[slot]   = (unsigned)(c * N_PROP + s);
            keptBox[slot]   = make_float4(0.0f, 0.0f, 0.0f, 0.0f);
        }
    }
}

// ---------------- Kernel 3: global top-100 via LDS rank (conflict-free) ---
// 64 elements/block, 4 threads/element; part-strided scan j = part + 4*i so
// each wave instruction reads 4 consecutive u64 (broadcast across the 16
// element-groups) -> zero bank conflicts.
__global__ __launch_bounds__(256) void k_topk(
    const float* __restrict__ keptScore,
    const unsigned* __restrict__ keptKey,
    const float4* __restrict__ keptBox,
    float* __restrict__ out)            // [100] scores | [400] boxes | [100] labels
{
    __shared__ unsigned long long pk[KEPT_CAP];
    const int blockStart = blockIdx.x * 64;

    for (int j = threadIdx.x; j < KEPT_CAP; j += 256) {
        pk[j] = ((unsigned long long)__float_as_uint(keptScore[j]) << 32)
              | (unsigned)(~keptKey[j]);
    }
    __syncthreads();

    const int e    = blockStart + (threadIdx.x >> 2);
    const int part = threadIdx.x & 3;
    const unsigned long long mykey = pk[e];

    int r = 0;
    for (int j = part; j < KEPT_CAP; j += 32) {     // 8 reads/iter, stride 4
        const unsigned long long k0 = pk[j + 0 * 4];
        const unsigned long long k1 = pk[j + 1 * 4];
        const unsigned long long k2 = pk[j + 2 * 4];
        const unsigned long long k3 = pk[j + 3 * 4];
        const unsigned long long k4 = pk[j + 4 * 4];
        const unsigned long long k5 = pk[j + 5 * 4];
        const unsigned long long k6 = pk[j + 6 * 4];
        const unsigned long long k7 = pk[j + 7 * 4];
        r += (int)(k0 > mykey) + (int)(k1 > mykey)
           + (int)(k2 > mykey) + (int)(k3 > mykey)
           + (int)(k4 > mykey) + (int)(k5 > mykey)
           + (int)(k6 > mykey) + (int)(k7 > mykey);
    }

    r += __shfl_xor(r, 1);
    r += __shfl_xor(r, 2);

    if (part == 0 && r < DET_PER_IMG) {
        const float sc = keptScore[e];
        const bool valid = sc > 0.0f;
        out[r] = sc;
        const float4 b = keptBox[e];
        out[DET_PER_IMG + r * 4 + 0] = b.x;
        out[DET_PER_IMG + r * 4 + 1] = b.y;
        out[DET_PER_IMG + r * 4 + 2] = b.z;
        out[DET_PER_IMG + r * 4 + 3] = b.w;
        const unsigned key = keptKey[e];
        out[DET_PER_IMG * 5 + r] = valid ? (float)(key / N_PROP + 1) : 0.0f;
    }
}

extern "C" void kernel_launch(void* const* d_in, const int* in_sizes, int n_in,
                              void* d_out, int out_size, void* d_ws, size_t ws_size,
                              hipStream_t stream) {
    const float* logits = (const float*)d_in[0];
    const float* deltas = (const float*)d_in[1];
    const float* pboxes = (const float*)d_in[2];
    const int*   ih     = (const int*)d_in[3];
    const int*   iw     = (const int*)d_in[4];
    float* out = (float*)d_out;

    char* p = (char*)d_ws;
    float4*   keptBox   = (float4*)p;    p += (size_t)KEPT_CAP * 16;
    float*    candS     = (float*)p;     p += (size_t)NFG * N_PROP * 4;
    float*    keptScore = (float*)p;     p += (size_t)KEPT_CAP * 4;
    unsigned* keptKey   = (unsigned*)p;  p += (size_t)KEPT_CAP * 4;

    k_decode<<<N_PROP, 128, 0, stream>>>(logits, candS);
    k_nms<<<NFG, 256, 0, stream>>>(candS, deltas, pboxes, ih, iw,
                                   keptScore, keptKey, keptBox);
    k_topk<<<KEPT_CAP / 64, 256, 0, stream>>>(keptScore, keptKey, keptBox, out);
}

// Round 8
// 49.119 us; speedup vs baseline: 2.6672x; 1.4987x over previous
//
#include <hip/hip_runtime.h>
#include <math.h>

#define N_PROP 1000
#define NUM_CLASSES 81
#define NFG 80
#define SCORE_THRESH 0.05f
#define NMS_THRESH 0.5f
#define DET_PER_IMG 100
#define PER_CLASS_CAP 100
#define KEPT_CAP (NFG * PER_CLASS_CAP)   /* 8000, fixed */
#define MBITS 512                        /* bitmask NMS path when M <= MBITS */
#define SURV_CAP 4800
// log(1000/16)
#define BBOX_XFORM_CLIP 4.135166556742356f

// ---------------- Kernel 1: parallel softmax -> dense score grid ----------
__global__ __launch_bounds__(128) void k_decode(
    const float* __restrict__ logits,   // [N_PROP, 81]
    float* __restrict__ candS)          // [NFG][N_PROP]
{
    const int n = blockIdx.x;
    const int t = threadIdx.x;
    __shared__ float redm[2];
    __shared__ float reds[2];

    float l = (t < NUM_CLASSES) ? logits[n * NUM_CLASSES + t] : -INFINITY;

    float m = l;
    #pragma unroll
    for (int o = 32; o > 0; o >>= 1) m = fmaxf(m, __shfl_xor(m, o));
    const int wave = t >> 6;
    if ((t & 63) == 0) redm[wave] = m;
    __syncthreads();
    m = fmaxf(redm[0], redm[1]);

    float e = (t < NUM_CLASSES) ? expf(l - m) : 0.0f;
    float s = e;
    #pragma unroll
    for (int o = 32; o > 0; o >>= 1) s += __shfl_xor(s, o);
    if ((t & 63) == 0) reds[wave] = s;
    __syncthreads();
    s = reds[0] + reds[1];

    if (t >= 1 && t < NUM_CLASSES) {
        const float prob = e / s;
        candS[(size_t)(t - 1) * N_PROP + n] = (prob > SCORE_THRESH) ? prob : 0.0f;
    }
}

// ---------------- Kernel 2: per-class compact+decode+sort + bitmask NMS ---
__global__ __launch_bounds__(256) void k_nms(
    const float* __restrict__ candS,
    const float* __restrict__ deltas,   // [N_PROP, 324]
    const float* __restrict__ pboxes,   // [N_PROP, 4]
    const int* __restrict__ ih, const int* __restrict__ iw,
    float* __restrict__ keptScore,      // [KEPT_CAP]
    unsigned* __restrict__ keptKey,     // [KEPT_CAP]
    float4* __restrict__ keptBox)       // [KEPT_CAP]
{
    const int c   = blockIdx.x;
    const int cls = c + 1;
    const int tid = threadIdx.x;

    __shared__ union {
        struct { float ss[N_PROP]; int si[N_PROP]; float sb[N_PROP * 4]; } in;
        unsigned long long msk[MBITS * (MBITS / 64)];
    } u;
    __shared__ float os[N_PROP];
    __shared__ float ob[N_PROP * 4];
    __shared__ unsigned long long keepw_s[16];
    __shared__ int cnt;

    if (tid == 0) cnt = 0;
    __syncthreads();

    const float W = (float)iw[0] - 1.0f;
    const float H = (float)ih[0] - 1.0f;

    for (int n = tid; n < N_PROP; n += 256) {
        const float p = candS[(size_t)c * N_PROP + n];
        if (p > 0.0f) {
            const float x1b = pboxes[n * 4 + 0];
            const float y1b = pboxes[n * 4 + 1];
            const float x2b = pboxes[n * 4 + 2];
            const float y2b = pboxes[n * 4 + 3];
            const float w  = x2b - x1b + 1.0f;
            const float h  = y2b - y1b + 1.0f;
            const float cx = x1b + 0.5f * w;
            const float cy = y1b + 0.5f * h;
            const float* d = deltas + (size_t)n * (NUM_CLASSES * 4) + cls * 4;
            const float dx = d[0] / 10.0f;
            const float dy = d[1] / 10.0f;
            const float dw = fminf(d[2] / 5.0f, BBOX_XFORM_CLIP);
            const float dh = fminf(d[3] / 5.0f, BBOX_XFORM_CLIP);
            const float pcx = dx * w + cx;
            const float pcy = dy * h + cy;
            const float pw  = expf(dw) * w;
            const float ph  = expf(dh) * h;
            float X1 = pcx - 0.5f * pw;
            float Y1 = pcy - 0.5f * ph;
            float X2 = pcx + 0.5f * pw - 1.0f;
            float Y2 = pcy + 0.5f * ph - 1.0f;
            X1 = fminf(fmaxf(X1, 0.0f), W);
            Y1 = fminf(fmaxf(Y1, 0.0f), H);
            X2 = fminf(fmaxf(X2, 0.0f), W);
            Y2 = fminf(fmaxf(Y2, 0.0f), H);

            const int pos = atomicAdd(&cnt, 1);
            u.in.ss[pos] = p;
            u.in.si[pos] = n;
            u.in.sb[pos * 4 + 0] = X1;
            u.in.sb[pos * 4 + 1] = Y1;
            u.in.sb[pos * 4 + 2] = X2;
            u.in.sb[pos * 4 + 3] = Y2;
        }
    }
    __syncthreads();
    const int M = cnt;

    // rank sort: (score desc, prop_idx asc)
    for (int i = tid; i < M; i += 256) {
        const float s0 = u.in.ss[i];
        const int   i0 = u.in.si[i];
        int r = 0;
        for (int j = 0; j < M; ++j) {
            const float sj = u.in.ss[j];
            r += (sj > s0) || (sj == s0 && u.in.si[j] < i0);
        }
        os[r] = s0;
        ob[r * 4 + 0] = u.in.sb[i * 4 + 0];
        ob[r * 4 + 1] = u.in.sb[i * 4 + 1];
        ob[r * 4 + 2] = u.in.sb[i * 4 + 2];
        ob[r * 4 + 3] = u.in.sb[i * 4 + 3];
    }
    __syncthreads();

    if (M <= MBITS) {
        const int NW = (M + 63) >> 6;

        for (int idx = tid; idx < M * NW; idx += 256) {
            const int i = idx / NW;
            const int w = idx - i * NW;
            const float ax1 = ob[i * 4 + 0], ay1 = ob[i * 4 + 1];
            const float ax2 = ob[i * 4 + 2], ay2 = ob[i * 4 + 3];
            const float aarea = (ax2 - ax1 + 1.0f) * (ay2 - ay1 + 1.0f);
            unsigned long long bits = 0;
            const int j0 = w << 6;
            const int jb = (i + 1 > j0) ? (i + 1) : j0;
            const int je = (j0 + 64 < M) ? (j0 + 64) : M;
            for (int j = jb; j < je; ++j) {
                const float bx1 = ob[j * 4 + 0], by1 = ob[j * 4 + 1];
                const float bx2 = ob[j * 4 + 2], by2 = ob[j * 4 + 3];
                const float barea = (bx2 - bx1 + 1.0f) * (by2 - by1 + 1.0f);
                const float ix1 = fmaxf(ax1, bx1), iy1 = fmaxf(ay1, by1);
                const float ix2 = fminf(ax2, bx2), iy2 = fminf(ay2, by2);
                const float iw_ = fmaxf(ix2 - ix1 + 1.0f, 0.0f);
                const float ih_ = fmaxf(iy2 - iy1 + 1.0f, 0.0f);
                const float inter = iw_ * ih_;
                const float iou = inter / (aarea + barea - inter);
                if (iou > NMS_THRESH) bits |= 1ull << (j - j0);
            }
            u.msk[i * NW + w] = bits;
        }
        __syncthreads();

        if (tid < 64) {
            const int l = tid;
            const int base = l << 6;
            int nb = M - base;
            nb = nb < 0 ? 0 : (nb > 64 ? 64 : nb);
            unsigned long long keepw =
                (nb == 64) ? ~0ull : ((nb == 0) ? 0ull : ((1ull << nb) - 1ull));
            for (int i = 0; i < M; ++i) {
                const unsigned long long kb = __shfl(keepw, i >> 6);
                if ((kb >> (i & 63)) & 1ull) {
                    const unsigned long long mrow =
                        (l < NW) ? u.msk[i * NW + l] : 0ull;
                    keepw &= ~mrow;
                }
            }
            if (l < 16) keepw_s[l] = keepw;
        }
        __syncthreads();

        unsigned long long kw[16];
        #pragma unroll
        for (int w = 0; w < 16; ++w) kw[w] = keepw_s[w];
        int S = 0;
        #pragma unroll
        for (int w = 0; w < 16; ++w) S += __popcll(kw[w]);
        if (S > PER_CLASS_CAP) S = PER_CLASS_CAP;

        for (int i = tid; i < M; i += 256) {
            const int w = i >> 6, b = i & 63;
            if ((kw[w] >> b) & 1ull) {
                int sr = 0;
                for (int ww = 0; ww < w; ++ww) sr += __popcll(kw[ww]);
                sr += __popcll(kw[w] & ((b == 0) ? 0ull : (~0ull >> (64 - b))));
                if (sr < PER_CLASS_CAP) {
                    const int slot = c * PER_CLASS_CAP + sr;
                    keptScore[slot] = os[i];
                    keptKey[slot]   = (unsigned)(c * N_PROP + i);
                    keptBox[slot]   = make_float4(ob[i * 4 + 0], ob[i * 4 + 1],
                                                  ob[i * 4 + 2], ob[i * 4 + 3]);
                }
            }
        }
        for (int s = S + tid; s < PER_CLASS_CAP; s += 256) {
            const int slot = c * PER_CLASS_CAP + s;
            keptScore[slot] = 0.0f;
            keptKey[slot]   = (unsigned)(c * N_PROP + s);
            keptBox[slot]   = make_float4(0.0f, 0.0f, 0.0f, 0.0f);
        }
    } else {
        // legacy serial path (M > 512; never hit by this data)
        int* ok = (int*)u.msk;
        for (int i = tid; i < M; i += 256) ok[i] = 1;
        __syncthreads();
        for (int i = 0; i < M; ++i) {
            if (ok[i]) {
                const float ax1 = ob[i * 4 + 0], ay1 = ob[i * 4 + 1];
                const float ax2 = ob[i * 4 + 2], ay2 = ob[i * 4 + 3];
                const float aarea = (ax2 - ax1 + 1.0f) * (ay2 - ay1 + 1.0f);
                for (int j = i + 1 + tid; j < M; j += 256) {
                    const float bx1 = ob[j * 4 + 0], by1 = ob[j * 4 + 1];
                    const float bx2 = ob[j * 4 + 2], by2 = ob[j * 4 + 3];
                    const float barea = (bx2 - bx1 + 1.0f) * (by2 - by1 + 1.0f);
                    const float ix1 = fmaxf(ax1, bx1), iy1 = fmaxf(ay1, by1);
                    const float ix2 = fminf(ax2, bx2), iy2 = fminf(ay2, by2);
                    const float iw_ = fmaxf(ix2 - ix1 + 1.0f, 0.0f);
                    const float ih_ = fmaxf(iy2 - iy1 + 1.0f, 0.0f);
                    const float inter = iw_ * ih_;
                    const float iou = inter / (aarea + barea - inter);
                    if (iou > NMS_THRESH) ok[j] = 0;
                }
            }
            __syncthreads();
        }
        for (int i = tid; i < M; i += 256) {
            if (ok[i]) {
                int sr = 0;
                for (int j = 0; j < i; ++j) sr += ok[j];
                if (sr < PER_CLASS_CAP) {
                    const int slot = c * PER_CLASS_CAP + sr;
                    keptScore[slot] = os[i];
                    keptKey[slot]   = (unsigned)(c * N_PROP + i);
                    keptBox[slot]   = make_float4(ob[i * 4 + 0], ob[i * 4 + 1],
                                                  ob[i * 4 + 2], ob[i * 4 + 3]);
                }
            }
        }
        int S = 0;
        for (int j = 0; j < M; ++j) S += ok[j];
        if (S > PER_CLASS_CAP) S = PER_CLASS_CAP;
        for (int s = S + tid; s < PER_CLASS_CAP; s += 256) {
            const int slot = c * PER_CLASS_CAP + s;
            keptScore[slot] = 0.0f;
            keptKey[slot]   = (unsigned)(c * N_PROP + s);
            keptBox[slot]   = make_float4(0.0f, 0.0f, 0.0f, 0.0f);
        }
    }
}

// bucket over score-bits: monotone; scores in (0.05,1) -> buckets ~460..1023;
// zero/invalid -> bucket 0.
__device__ __forceinline__ int bucket_of_bits(unsigned bits) {
    int b = (int)(bits >> 16) - 15232;
    b = b < 0 ? 0 : b;
    return b > 1023 ? 1023 : b;
}

// ---------------- Kernel 3: top-100 via histogram select (ONE block) ------
// Histogram 8000 score-bits -> suffix-sum -> threshold bucket B* of the
// 100th-largest -> compact survivors (bucket >= B*, Ns ~ 100-150) -> exact
// all-pairs rank among survivors only. Survivor count >= 100 guaranteed, so
// every output rank 0..99 is written exactly once per call.
__global__ __launch_bounds__(1024) void k_topk(
    const float* __restrict__ keptScore,
    const unsigned* __restrict__ keptKey,
    const float4* __restrict__ keptBox,
    float* __restrict__ out)            // [100] scores | [400] boxes | [100] labels
{
    __shared__ union {
        struct {
            int hist[1024];
            int S[1024];
            unsigned long long spk[SURV_CAP];
            unsigned short sid[SURV_CAP];
        } sel;                                   // 56192 B
        unsigned long long pk[KEPT_CAP];         // 64000 B (fallback)
    } u;
    __shared__ int ns_s;
    __shared__ int bstar_s;
    const int tid = threadIdx.x;

    u.sel.hist[tid] = 0;
    __syncthreads();

    for (int e = tid; e < KEPT_CAP; e += 1024) {
        const int b = bucket_of_bits(__float_as_uint(keptScore[e]));
        atomicAdd(&u.sel.hist[b], 1);
    }
    __syncthreads();

    // suffix sum: S[b] = #entries in buckets >= b
    u.sel.S[tid] = u.sel.hist[tid];
    __syncthreads();
    for (int d = 1; d < 1024; d <<= 1) {
        const int v = (tid + d < 1024) ? u.sel.S[tid + d] : 0;
        __syncthreads();
        u.sel.S[tid] += v;
        __syncthreads();
    }

    // B* = bucket of the 100th-largest (S non-increasing; S[0]=8000 -> exists)
    if (tid == 0) ns_s = 0;
    if (u.sel.S[tid] >= DET_PER_IMG &&
        (tid == 1023 || u.sel.S[tid + 1] < DET_PER_IMG))
        bstar_s = tid;
    __syncthreads();
    const int Bstar = bstar_s;

    // compact survivors
    for (int e = tid; e < KEPT_CAP; e += 1024) {
        const unsigned bits = __float_as_uint(keptScore[e]);
        if (bucket_of_bits(bits) >= Bstar) {
            const int pos = atomicAdd(&ns_s, 1);
            if (pos < SURV_CAP) {
                u.sel.spk[pos] = ((unsigned long long)bits << 32)
                               | (unsigned)(~keptKey[e]);
                u.sel.sid[pos] = (unsigned short)e;
            }
        }
    }
    __syncthreads();
    const int ns = ns_s;

    if (ns <= SURV_CAP) {
        for (int i = tid; i < ns; i += 1024) {
            const unsigned long long mykey = u.sel.spk[i];
            int r = 0;
            for (int j = 0; j < ns; ++j) r += (int)(u.sel.spk[j] > mykey);
            if (r < DET_PER_IMG) {
                const int e = u.sel.sid[i];
                const float sc = keptScore[e];
                const bool valid = sc > 0.0f;
                out[r] = sc;
                const float4 b = keptBox[e];
                out[DET_PER_IMG + r * 4 + 0] = b.x;
                out[DET_PER_IMG + r * 4 + 1] = b.y;
                out[DET_PER_IMG + r * 4 + 2] = b.z;
                out[DET_PER_IMG + r * 4 + 3] = b.w;
                const unsigned key = keptKey[e];
                out[DET_PER_IMG * 5 + r] = valid ? (float)(key / N_PROP + 1) : 0.0f;
            }
        }
    } else {
        // tie-storm fallback: full in-block rank (correct, slow; never hit)
        __syncthreads();
        for (int j = tid; j < KEPT_CAP; j += 1024)
            u.pk[j] = ((unsigned long long)__float_as_uint(keptScore[j]) << 32)
                    | (unsigned)(~keptKey[j]);
        __syncthreads();
        for (int e = tid; e < KEPT_CAP; e += 1024) {
            const unsigned long long mykey = u.pk[e];
            int r = 0;
            for (int j = 0; j < KEPT_CAP; ++j) r += (int)(u.pk[j] > mykey);
            if (r < DET_PER_IMG) {
                const float sc = keptScore[e];
                const bool valid = sc > 0.0f;
                out[r] = sc;
                const float4 b = keptBox[e];
                out[DET_PER_IMG + r * 4 + 0] = b.x;
                out[DET_PER_IMG + r * 4 + 1] = b.y;
                out[DET_PER_IMG + r * 4 + 2] = b.z;
                out[DET_PER_IMG + r * 4 + 3] = b.w;
                const unsigned key = keptKey[e];
                out[DET_PER_IMG * 5 + r] = valid ? (float)(key / N_PROP + 1) : 0.0f;
            }
        }
    }
}

extern "C" void kernel_launch(void* const* d_in, const int* in_sizes, int n_in,
                              void* d_out, int out_size, void* d_ws, size_t ws_size,
                              hipStream_t stream) {
    const float* logits = (const float*)d_in[0];
    const float* deltas = (const float*)d_in[1];
    const float* pboxes = (const float*)d_in[2];
    const int*   ih     = (const int*)d_in[3];
    const int*   iw     = (const int*)d_in[4];
    float* out = (float*)d_out;

    char* p = (char*)d_ws;
    float4*   keptBox   = (float4*)p;    p += (size_t)KEPT_CAP * 16;
    float*    candS     = (float*)p;     p += (size_t)NFG * N_PROP * 4;
    float*    keptScore = (float*)p;     p += (size_t)KEPT_CAP * 4;
    unsigned* keptKey   = (unsigned*)p;  p += (size_t)KEPT_CAP * 4;

    k_decode<<<N_PROP, 128, 0, stream>>>(logits, candS);
    k_nms<<<NFG, 256, 0, stream>>>(candS, deltas, pboxes, ih, iw,
                                   keptScore, keptKey, keptBox);
    k_topk<<<1, 1024, 0, stream>>>(keptScore, keptKey, keptBox, out);
}